// Round 1
// baseline (167.626 us; speedup 1.0000x reference)
//
#include <hip/hip_runtime.h>
#include <hip/hip_bf16.h>

// loss = (100/N^2) * [3*s_tt + s_rr + s_dd + s_ii - 2*(s_tr + s_td + s_ti)]
// where s_ab = || n_a^T n_b ||_F^2   (n_x = row-normalized input, N=4096, D=512)
//
// Pipeline:
//   K1 rownorm:    rscale[mod][r] = 1/max(||row||,eps)            (reads 32 MB)
//   K2 transpose:  nT[mod][c][k]  = bf16(X[k][c]*rscale)  K-contig (reads 32 MB, writes 16 MB)
//   K3 gram_frob:  7 TN-GEMMs 512x512x4096 via mfma_f32_16x16x32_bf16,
//                  Frobenius-reduce tiles -> atomicAdd(d_out)      (15.4 GFLOP)

typedef __attribute__((ext_vector_type(8))) short short8;
typedef __attribute__((ext_vector_type(4))) float floatx4;

#define N_ROWS 4096
#define DDIM   512
#define NT_ELEMS ((size_t)4 * DDIM * N_ROWS)   // 8M bf16 = 16 MB
#define LOSS_SCALE 5.9604644775390625e-06f      // 100 / 4096^2

__global__ __launch_bounds__(256) void rownorm_kernel(
    const float* __restrict__ in0, const float* __restrict__ in1,
    const float* __restrict__ in2, const float* __restrict__ in3,
    float* __restrict__ rscale) {
  int row = blockIdx.x;            // 0..16383  (mod*4096 + r)
  int mod = row >> 12;
  int r   = row & 4095;
  const float* x = (mod == 0 ? in0 : mod == 1 ? in1 : mod == 2 ? in2 : in3);
  x += (size_t)r * DDIM;
  int t = threadIdx.x;             // 0..255, 2 floats each
  float2 v = ((const float2*)x)[t];
  float ss = v.x * v.x + v.y * v.y;
#pragma unroll
  for (int off = 32; off > 0; off >>= 1) ss += __shfl_down(ss, off, 64);
  __shared__ float wsum[4];
  if ((t & 63) == 0) wsum[t >> 6] = ss;
  __syncthreads();
  if (t == 0) {
    float s = wsum[0] + wsum[1] + wsum[2] + wsum[3];
    float nrm = sqrtf(s);
    rscale[row] = 1.0f / fmaxf(nrm, 1e-12f);
  }
}

__global__ __launch_bounds__(256) void transpose_kernel(
    const float* __restrict__ in0, const float* __restrict__ in1,
    const float* __restrict__ in2, const float* __restrict__ in3,
    const float* __restrict__ rscale, unsigned short* __restrict__ nT) {
  // grid: x = 64 (64-row tiles over N), y = 8 (64-col tiles over D), z = 4 (mod)
  int mod = blockIdx.z;
  int r0 = blockIdx.x * 64;
  int c0 = blockIdx.y * 64;
  const float* x = (mod == 0 ? in0 : mod == 1 ? in1 : mod == 2 ? in2 : in3);
  __shared__ unsigned short tile[64][65];   // +1 pad: transposed reads ~2-way (free)
  int t = threadIdx.x;
  int tr = t >> 6;      // wave id 0..3
  int tc = t & 63;      // lane
#pragma unroll
  for (int i = 0; i < 16; ++i) {
    int rr = i * 4 + tr;
    int r = r0 + rr;
    float sc = rscale[mod * N_ROWS + r];          // wave-uniform broadcast
    float v = x[(size_t)r * DDIM + c0 + tc] * sc; // coalesced 256B/wave
    __hip_bfloat16 h = __float2bfloat16(v);       // RNE
    tile[rr][tc] = *reinterpret_cast<unsigned short*>(&h);
  }
  __syncthreads();
  unsigned short* out = nT + ((size_t)mod * DDIM + c0) * N_ROWS + r0;
#pragma unroll
  for (int i = 0; i < 16; ++i) {
    int cc = i * 4 + tr;
    out[(size_t)cc * N_ROWS + tc] = tile[tc][cc]; // coalesced 128B/wave
  }
}

__global__ __launch_bounds__(256) void gram_frob_kernel(
    const unsigned short* __restrict__ nT, float* __restrict__ out) {
  // blockIdx.x = tile 0..15 (4x4 over 512x512), blockIdx.y = product 0..6
  __shared__ unsigned short lsA[128 * 64];  // 16 KB, rows K-contiguous
  __shared__ unsigned short lsB[128 * 64];  // 16 KB
  __shared__ float red[4];

  const int   pa[7] = {3, 0, 1, 2, 3, 3, 3};
  const int   pb[7] = {3, 0, 1, 2, 0, 1, 2};
  const float pw[7] = {3.f, 1.f, 1.f, 1.f, -2.f, -2.f, -2.f};

  int tile = blockIdx.x;
  int prod = blockIdx.y;
  int a0 = (tile >> 2) * 128;
  int b0 = (tile & 3) * 128;
  const unsigned short* Abase = nT + ((size_t)pa[prod] * DDIM + a0) * N_ROWS;
  const unsigned short* Bbase = nT + ((size_t)pb[prod] * DDIM + b0) * N_ROWS;

  int t = threadIdx.x;
  int wave = t >> 6;
  int lane = t & 63;
  int wr = (wave >> 1) * 64;   // wave's 64x64 quadrant of the 128x128 tile
  int wc = (wave & 1) * 64;
  int lm = lane & 15;          // MFMA 16-dim index
  int lq = lane >> 4;          // quad -> k-chunk of 8

  floatx4 zero = {0.f, 0.f, 0.f, 0.f};
  floatx4 acc[4][4];
#pragma unroll
  for (int mi = 0; mi < 4; ++mi)
#pragma unroll
    for (int ni = 0; ni < 4; ++ni) acc[mi][ni] = zero;

  int srow = lane >> 3;          // 0..7: row within 8-row staging group
  int scol = (lane & 7) * 8;     // 16B = 8 bf16 within the 64-elem row

  for (int k0 = 0; k0 < N_ROWS; k0 += 64) {
#pragma unroll
    for (int c = 0; c < 4; ++c) {
      int base_row = wave * 32 + c * 8;            // wave-uniform
      const unsigned short* ga =
          Abase + (size_t)(base_row + srow) * N_ROWS + k0 + scol;
      const unsigned short* gb =
          Bbase + (size_t)(base_row + srow) * N_ROWS + k0 + scol;
      __builtin_amdgcn_global_load_lds(
          (__attribute__((address_space(1))) void*)(void*)ga,
          (__attribute__((address_space(3))) void*)(void*)&lsA[base_row * 64],
          16, 0, 0);
      __builtin_amdgcn_global_load_lds(
          (__attribute__((address_space(1))) void*)(void*)gb,
          (__attribute__((address_space(3))) void*)(void*)&lsB[base_row * 64],
          16, 0, 0);
    }
    __syncthreads();   // compiler emits vmcnt(0) drain here

#pragma unroll
    for (int ks = 0; ks < 2; ++ks) {
      short8 af[4], bf[4];
#pragma unroll
      for (int mi = 0; mi < 4; ++mi) {
        int row = wr + mi * 16 + lm;
        af[mi] = *(const short8*)&lsA[row * 64 + ks * 32 + lq * 8]; // ds_read_b128
      }
#pragma unroll
      for (int ni = 0; ni < 4; ++ni) {
        int row = wc + ni * 16 + lm;
        bf[ni] = *(const short8*)&lsB[row * 64 + ks * 32 + lq * 8];
      }
#pragma unroll
      for (int mi = 0; mi < 4; ++mi)
#pragma unroll
        for (int ni = 0; ni < 4; ++ni)
          acc[mi][ni] = __builtin_amdgcn_mfma_f32_16x16x32_bf16(
              af[mi], bf[ni], acc[mi][ni], 0, 0, 0);
    }
    __syncthreads();
  }

  // Frobenius partial: C/D lane->element mapping is a bijection, so layout
  // is irrelevant for sum-of-squares.
  float s = 0.f;
#pragma unroll
  for (int mi = 0; mi < 4; ++mi)
#pragma unroll
    for (int ni = 0; ni < 4; ++ni)
#pragma unroll
      for (int r = 0; r < 4; ++r) {
        float v = acc[mi][ni][r];
        s += v * v;
      }
#pragma unroll
  for (int off = 32; off > 0; off >>= 1) s += __shfl_down(s, off, 64);
  if (lane == 0) red[wave] = s;
  __syncthreads();
  if (t == 0) {
    float tot = red[0] + red[1] + red[2] + red[3];
    atomicAdd(out, pw[prod] * LOSS_SCALE * tot);
  }
}

extern "C" void kernel_launch(void* const* d_in, const int* in_sizes, int n_in,
                              void* d_out, int out_size, void* d_ws, size_t ws_size,
                              hipStream_t stream) {
  const float* in_rgb   = (const float*)d_in[0];
  const float* in_depth = (const float*)d_in[1];
  const float* in_ir    = (const float*)d_in[2];
  const float* in_t     = (const float*)d_in[3];

  unsigned short* nT = (unsigned short*)d_ws;                 // 16 MB bf16 nT
  float* rscale = (float*)((char*)d_ws + NT_ELEMS * sizeof(unsigned short)); // 64 KB

  hipMemsetAsync(d_out, 0, out_size * sizeof(float), stream);

  rownorm_kernel<<<4 * N_ROWS, 256, 0, stream>>>(in_rgb, in_depth, in_ir, in_t,
                                                 rscale);
  transpose_kernel<<<dim3(N_ROWS / 64, DDIM / 64, 4), 256, 0, stream>>>(
      in_rgb, in_depth, in_ir, in_t, rscale, nT);
  gram_frob_kernel<<<dim3(16, 7), 256, 0, stream>>>(nT, (float*)d_out);
}

// Round 2
// 152.580 us; speedup vs baseline: 1.0986x; 1.0986x over previous
//
#include <hip/hip_runtime.h>
#include <hip/hip_bf16.h>

// loss = (100/N^2) * [3*s_tt + s_rr + s_dd + s_ii - 2*(s_tr + s_td + s_ti)]
// where s_ab = || n_a^T n_b ||_F^2   (n_x = row-normalized input, N=4096, D=512)
//
// K1 preprocess: fused rownorm + scale + bf16 cast + transpose -> nT[mod][c][k]
// K2 gram_frob:  7 TN-GEMMs 512x512x4096, 128x128 tiles, XOR-swizzled LDS,
//                double-buffered global_load_lds staging, Frobenius reduce.

typedef __attribute__((ext_vector_type(8))) short short8;
typedef __attribute__((ext_vector_type(4))) float floatx4;

#define N_ROWS 4096
#define DDIM   512
#define NT_ELEMS ((size_t)4 * DDIM * N_ROWS)   // 8M bf16 = 16 MB
#define LOSS_SCALE 5.9604644775390625e-06f      // 100 / 4096^2

__global__ __launch_bounds__(512) void preprocess_kernel(
    const float* __restrict__ in0, const float* __restrict__ in1,
    const float* __restrict__ in2, const float* __restrict__ in3,
    unsigned short* __restrict__ nT) {
  // grid: x = 32 (128-row strips over N), y = 4 (mod). 512 threads = 8 waves.
  int mod = blockIdx.y;
  const float* X = (mod == 0 ? in0 : mod == 1 ? in1 : mod == 2 ? in2 : in3);
  X += (size_t)blockIdx.x * 128 * DDIM;
  unsigned short* out = nT + (size_t)mod * DDIM * N_ROWS + blockIdx.x * 128;

  __shared__ float rsc[128];
  __shared__ unsigned short tile[64][130];  // [col][row(128)+pad2]

  int t = threadIdx.x;
  int w = t >> 6;        // wave 0..7
  int lane = t & 63;

  // phase 1: row norms (16 rows per wave, coalesced float4 x2 per lane)
#pragma unroll
  for (int i = 0; i < 16; ++i) {
    int r = i * 8 + w;
    const float4* rp = (const float4*)(X + (size_t)r * DDIM);
    float4 a = rp[2 * lane];
    float4 b = rp[2 * lane + 1];
    float ss = a.x * a.x + a.y * a.y + a.z * a.z + a.w * a.w +
               b.x * b.x + b.y * b.y + b.z * b.z + b.w * b.w;
#pragma unroll
    for (int off = 32; off > 0; off >>= 1) ss += __shfl_down(ss, off, 64);
    if (lane == 0) rsc[r] = 1.0f / fmaxf(sqrtf(ss), 1e-12f);
  }
  __syncthreads();

  // phase 2: 8 panels of 64 cols; scale+cast into LDS transposed, write out
  for (int p = 0; p < 8; ++p) {
#pragma unroll
    for (int i = 0; i < 16; ++i) {
      int rr = i * 8 + w;
      float v = X[(size_t)rr * DDIM + p * 64 + lane] * rsc[rr];  // L2-warm
      __hip_bfloat16 h = __float2bfloat16(v);
      tile[lane][rr] = *reinterpret_cast<unsigned short*>(&h);
    }
    __syncthreads();
#pragma unroll
    for (int i = 0; i < 8; ++i) {
      int c = i * 8 + w;
      unsigned int v = ((const unsigned int*)&tile[c][0])[lane];  // 2 rows
      *(unsigned int*)(out + (size_t)(p * 64 + c) * N_ROWS + 2 * lane) = v;
    }
    __syncthreads();
  }
}

__device__ __forceinline__ void stage_tiles(
    const unsigned short* __restrict__ Abase,
    const unsigned short* __restrict__ Bbase, int k0,
    unsigned short* lsA, unsigned short* lsB, int wave, int lane) {
  // XOR swizzle: LDS slot s (=lane&7) of row r receives global chunk s ^ (r&7).
  int srow = lane >> 3;
  int scol = ((lane & 7) ^ srow) * 8;
#pragma unroll
  for (int c = 0; c < 4; ++c) {
    int base_row = wave * 32 + c * 8;  // wave-uniform
    const unsigned short* ga =
        Abase + (size_t)(base_row + srow) * N_ROWS + k0 + scol;
    const unsigned short* gb =
        Bbase + (size_t)(base_row + srow) * N_ROWS + k0 + scol;
    __builtin_amdgcn_global_load_lds(
        (__attribute__((address_space(1))) void*)(void*)ga,
        (__attribute__((address_space(3))) void*)(void*)&lsA[base_row * 64],
        16, 0, 0);
    __builtin_amdgcn_global_load_lds(
        (__attribute__((address_space(1))) void*)(void*)gb,
        (__attribute__((address_space(3))) void*)(void*)&lsB[base_row * 64],
        16, 0, 0);
  }
}

__device__ __forceinline__ void compute_tiles(
    const unsigned short* lsA, const unsigned short* lsB,
    floatx4 acc[4][4], int wr, int wc, int lm, int lq) {
#pragma unroll
  for (int ks = 0; ks < 2; ++ks) {
    int slot = (ks * 4 + lq) ^ (lm & 7);  // un-swizzle (row&7 == lm&7)
    short8 af[4], bf[4];
#pragma unroll
    for (int mi = 0; mi < 4; ++mi) {
      int row = wr + mi * 16 + lm;
      af[mi] = *(const short8*)&lsA[row * 64 + slot * 8];  // ds_read_b128
    }
#pragma unroll
    for (int ni = 0; ni < 4; ++ni) {
      int row = wc + ni * 16 + lm;
      bf[ni] = *(const short8*)&lsB[row * 64 + slot * 8];
    }
#pragma unroll
    for (int mi = 0; mi < 4; ++mi)
#pragma unroll
      for (int ni = 0; ni < 4; ++ni)
        acc[mi][ni] = __builtin_amdgcn_mfma_f32_16x16x32_bf16(
            af[mi], bf[ni], acc[mi][ni], 0, 0, 0);
  }
}

__global__ __launch_bounds__(256) void gram_frob_kernel(
    const unsigned short* __restrict__ nT, float* __restrict__ out) {
  // blockIdx.x = tile 0..15 (4x4 over 512x512), blockIdx.y = product 0..6
  __shared__ unsigned short ls[2][2][128 * 64];  // [buf][A/B], 64 KB total
  __shared__ float red[4];

  const int   pa[7] = {3, 0, 1, 2, 3, 3, 3};
  const int   pb[7] = {3, 0, 1, 2, 0, 1, 2};
  const float pw[7] = {3.f, 1.f, 1.f, 1.f, -2.f, -2.f, -2.f};

  int tile = blockIdx.x;
  int prod = blockIdx.y;
  int a0 = (tile >> 2) * 128;
  int b0 = (tile & 3) * 128;
  const unsigned short* Abase = nT + ((size_t)pa[prod] * DDIM + a0) * N_ROWS;
  const unsigned short* Bbase = nT + ((size_t)pb[prod] * DDIM + b0) * N_ROWS;

  int t = threadIdx.x;
  int wave = t >> 6;
  int lane = t & 63;
  int wr = (wave >> 1) * 64;
  int wc = (wave & 1) * 64;
  int lm = lane & 15;
  int lq = lane >> 4;

  floatx4 zero = {0.f, 0.f, 0.f, 0.f};
  floatx4 acc[4][4];
#pragma unroll
  for (int mi = 0; mi < 4; ++mi)
#pragma unroll
    for (int ni = 0; ni < 4; ++ni) acc[mi][ni] = zero;

  // Double-buffered pipeline: one barrier per chunk; the compiler's
  // vmcnt(0)-before-s_barrier lands AFTER compute, so the staging latency
  // is hidden behind MFMA instead of serialized in front of it.
  stage_tiles(Abase, Bbase, 0, ls[0][0], ls[0][1], wave, lane);
  __syncthreads();
  int k0 = 64;
  for (int i = 0; i < 31; ++i) {
    stage_tiles(Abase, Bbase, k0, ls[1][0], ls[1][1], wave, lane);
    compute_tiles(ls[0][0], ls[0][1], acc, wr, wc, lm, lq);
    __syncthreads();
    stage_tiles(Abase, Bbase, k0 + 64, ls[0][0], ls[0][1], wave, lane);
    compute_tiles(ls[1][0], ls[1][1], acc, wr, wc, lm, lq);
    __syncthreads();
    k0 += 128;
  }
  // tail: chunk 63 (k0 == 4032) into buf1; compute 3968 (buf0) then it
  stage_tiles(Abase, Bbase, 4032, ls[1][0], ls[1][1], wave, lane);
  compute_tiles(ls[0][0], ls[0][1], acc, wr, wc, lm, lq);
  __syncthreads();
  compute_tiles(ls[1][0], ls[1][1], acc, wr, wc, lm, lq);

  // Frobenius partial (C/D layout irrelevant for sum of squares)
  float s = 0.f;
#pragma unroll
  for (int mi = 0; mi < 4; ++mi)
#pragma unroll
    for (int ni = 0; ni < 4; ++ni)
#pragma unroll
      for (int r = 0; r < 4; ++r) {
        float v = acc[mi][ni][r];
        s += v * v;
      }
#pragma unroll
  for (int off = 32; off > 0; off >>= 1) s += __shfl_down(s, off, 64);
  if (lane == 0) red[wave] = s;
  __syncthreads();
  if (t == 0) {
    float tot = red[0] + red[1] + red[2] + red[3];
    atomicAdd(out, pw[prod] * LOSS_SCALE * tot);
  }
}

extern "C" void kernel_launch(void* const* d_in, const int* in_sizes, int n_in,
                              void* d_out, int out_size, void* d_ws, size_t ws_size,
                              hipStream_t stream) {
  const float* in_rgb   = (const float*)d_in[0];
  const float* in_depth = (const float*)d_in[1];
  const float* in_ir    = (const float*)d_in[2];
  const float* in_t     = (const float*)d_in[3];

  unsigned short* nT = (unsigned short*)d_ws;  // 16 MB bf16 nT

  hipMemsetAsync(d_out, 0, out_size * sizeof(float), stream);

  preprocess_kernel<<<dim3(32, 4), 512, 0, stream>>>(in_rgb, in_depth, in_ir,
                                                     in_t, nT);
  gram_frob_kernel<<<dim3(16, 7), 256, 0, stream>>>(nT, (float*)d_out);
}

// Round 3
// 129.299 us; speedup vs baseline: 1.2964x; 1.1801x over previous
//
#include <hip/hip_runtime.h>
#include <hip/hip_bf16.h>

// loss = (100/N^2) * [3*s_tt + s_rr + s_dd + s_ii - 2*(s_tr + s_td + s_ti)]
// where s_ab = || n_a^T n_b ||_F^2   (n_x = row-normalized input, N=4096, D=512)
//
// K1 rownorm:   rscale[mod][r] = 1/max(||row||,eps); also zeroes Cbuf (2048 blk)
// K2 transpose: nT[mod][c][k] = bf16(X[k][c]*rscale[k])  K-contig   (1024 blk)
// K3 gram:      7 TN-GEMMs 512x512, SPLIT-K=4 -> 448 blocks, 128x128 tiles,
//               XOR-swizzled dbuf LDS staging; partial C atomicAdd (positional,
//               layout-agnostic) into Cbuf
// K4 reduce:    sum_w( Cbuf^2 ) -> d_out

typedef __attribute__((ext_vector_type(8))) short short8;
typedef __attribute__((ext_vector_type(4))) float floatx4;

#define N_ROWS 4096
#define DDIM   512
#define NT_BYTES   ((size_t)4 * DDIM * N_ROWS * 2)        // 16 MB bf16
#define RSC_BYTES  ((size_t)4 * N_ROWS * 4)               // 64 KB
#define CBUF_ELEMS ((size_t)7 * 16 * 256 * 64)            // 1,835,008 fp32
#define LOSS_SCALE 5.9604644775390625e-06f                // 100 / 4096^2

__device__ __forceinline__ const float* sel_mod(int mod, const float* a,
                                                const float* b, const float* c,
                                                const float* d) {
  return mod == 0 ? a : mod == 1 ? b : mod == 2 ? c : d;
}

__global__ __launch_bounds__(256) void rownorm_kernel(
    const float* __restrict__ in0, const float* __restrict__ in1,
    const float* __restrict__ in2, const float* __restrict__ in3,
    float* __restrict__ rscale, float4* __restrict__ cz) {
  int t = threadIdx.x;
  // zero Cbuf (free: overlaps the norm loads)
  size_t zi = (size_t)blockIdx.x * 256 + t;
  if (zi < CBUF_ELEMS / 4) cz[zi] = float4{0.f, 0.f, 0.f, 0.f};

  int w = t >> 6, lane = t & 63;
  int base = blockIdx.x * 8;  // 8 rows/block, wave w does rows base+2w..+1
#pragma unroll
  for (int i = 0; i < 2; ++i) {
    int g = base + w * 2 + i;          // global row 0..16383
    int mod = g >> 12, r = g & 4095;
    const float* X = sel_mod(mod, in0, in1, in2, in3);
    const float4* rp = (const float4*)(X + (size_t)r * DDIM);
    float4 a = rp[lane];               // 1 KB dense per instr
    float4 b = rp[lane + 64];
    float ss = a.x * a.x + a.y * a.y + a.z * a.z + a.w * a.w +
               b.x * b.x + b.y * b.y + b.z * b.z + b.w * b.w;
#pragma unroll
    for (int off = 32; off > 0; off >>= 1) ss += __shfl_down(ss, off, 64);
    if (lane == 0) rscale[g] = 1.0f / fmaxf(sqrtf(ss), 1e-12f);
  }
}

__global__ __launch_bounds__(256) void transpose_kernel(
    const float* __restrict__ in0, const float* __restrict__ in1,
    const float* __restrict__ in2, const float* __restrict__ in3,
    const float* __restrict__ rscale, unsigned short* __restrict__ nT) {
  // grid: x = 64 (k-strips of 64), y = 4 (col-panels of 128), z = 4 (mod)
  int mod = blockIdx.z;
  int k0 = blockIdx.x * 64;
  int c0 = blockIdx.y * 128;
  const float* X = sel_mod(mod, in0, in1, in2, in3);

  __shared__ float lrsc[64];
  __shared__ unsigned short tile[128][66];  // [col][k+pad]

  int t = threadIdx.x;
  if (t < 64) lrsc[t] = rscale[mod * N_ROWS + k0 + t];
  __syncthreads();

#pragma unroll
  for (int it = 0; it < 8; ++it) {
    int idx = it * 256 + t;
    int r = idx >> 5;          // k-row 0..63
    int c4 = idx & 31;         // float4 index within 128-col panel
    float4 v = ((const float4*)(X + (size_t)(k0 + r) * DDIM + c0))[c4];
    float sc = lrsc[r];
    __hip_bfloat16 h0 = __float2bfloat16(v.x * sc);
    __hip_bfloat16 h1 = __float2bfloat16(v.y * sc);
    __hip_bfloat16 h2 = __float2bfloat16(v.z * sc);
    __hip_bfloat16 h3 = __float2bfloat16(v.w * sc);
    tile[c4 * 4 + 0][r] = *(unsigned short*)&h0;
    tile[c4 * 4 + 1][r] = *(unsigned short*)&h1;
    tile[c4 * 4 + 2][r] = *(unsigned short*)&h2;
    tile[c4 * 4 + 3][r] = *(unsigned short*)&h3;
  }
  __syncthreads();

#pragma unroll
  for (int it = 0; it < 8; ++it) {
    int idx = it * 256 + t;
    int c = idx >> 4;          // column 0..127
    int g = idx & 15;          // ushort4 group over k
    ushort4 v = *(ushort4*)&tile[c][g * 4];
    *(ushort4*)(nT + ((size_t)mod * DDIM + c0 + c) * N_ROWS + k0 + g * 4) = v;
  }
}

__device__ __forceinline__ void stage_tiles(
    const unsigned short* __restrict__ Abase,
    const unsigned short* __restrict__ Bbase, int k0,
    unsigned short* lsA, unsigned short* lsB, int wave, int lane) {
  // XOR swizzle: LDS slot s (=lane&7) of row r receives global chunk s ^ (r&7)
  int srow = lane >> 3;
  int scol = ((lane & 7) ^ srow) * 8;
#pragma unroll
  for (int c = 0; c < 4; ++c) {
    int base_row = wave * 32 + c * 8;  // wave-uniform
    const unsigned short* ga =
        Abase + (size_t)(base_row + srow) * N_ROWS + k0 + scol;
    const unsigned short* gb =
        Bbase + (size_t)(base_row + srow) * N_ROWS + k0 + scol;
    __builtin_amdgcn_global_load_lds(
        (__attribute__((address_space(1))) void*)(void*)ga,
        (__attribute__((address_space(3))) void*)(void*)&lsA[base_row * 64],
        16, 0, 0);
    __builtin_amdgcn_global_load_lds(
        (__attribute__((address_space(1))) void*)(void*)gb,
        (__attribute__((address_space(3))) void*)(void*)&lsB[base_row * 64],
        16, 0, 0);
  }
}

__device__ __forceinline__ void compute_tiles(
    const unsigned short* lsA, const unsigned short* lsB,
    floatx4 acc[4][4], int wr, int wc, int lm, int lq) {
#pragma unroll
  for (int ks = 0; ks < 2; ++ks) {
    int slot = (ks * 4 + lq) ^ (lm & 7);  // un-swizzle (row&7 == lm&7)
    short8 af[4], bf[4];
#pragma unroll
    for (int mi = 0; mi < 4; ++mi) {
      int row = wr + mi * 16 + lm;
      af[mi] = *(const short8*)&lsA[row * 64 + slot * 8];  // ds_read_b128
    }
#pragma unroll
    for (int ni = 0; ni < 4; ++ni) {
      int row = wc + ni * 16 + lm;
      bf[ni] = *(const short8*)&lsB[row * 64 + slot * 8];
    }
#pragma unroll
    for (int mi = 0; mi < 4; ++mi)
#pragma unroll
      for (int ni = 0; ni < 4; ++ni)
        acc[mi][ni] = __builtin_amdgcn_mfma_f32_16x16x32_bf16(
            af[mi], bf[ni], acc[mi][ni], 0, 0, 0);
  }
}

__global__ __launch_bounds__(256) void gram_frob_kernel(
    const unsigned short* __restrict__ nT, float* __restrict__ Cbuf) {
  // blockIdx: x = tile 0..15 (4x4 over 512x512), y = product 0..6, z = split 0..3
  __shared__ unsigned short ls[2][2][128 * 64];  // [buf][A/B], 64 KB

  const int pa[7] = {3, 0, 1, 2, 3, 3, 3};
  const int pb[7] = {3, 0, 1, 2, 0, 1, 2};

  int tile = blockIdx.x;
  int prod = blockIdx.y;
  int kbase = blockIdx.z * 1024;
  int a0 = (tile >> 2) * 128;
  int b0 = (tile & 3) * 128;
  const unsigned short* Abase = nT + ((size_t)pa[prod] * DDIM + a0) * N_ROWS;
  const unsigned short* Bbase = nT + ((size_t)pb[prod] * DDIM + b0) * N_ROWS;

  int t = threadIdx.x;
  int wave = t >> 6;
  int lane = t & 63;
  int wr = (wave >> 1) * 64;
  int wc = (wave & 1) * 64;
  int lm = lane & 15;
  int lq = lane >> 4;

  floatx4 zero = {0.f, 0.f, 0.f, 0.f};
  floatx4 acc[4][4];
#pragma unroll
  for (int mi = 0; mi < 4; ++mi)
#pragma unroll
    for (int ni = 0; ni < 4; ++ni) acc[mi][ni] = zero;

  // 16 chunks of K=64, double-buffered
  stage_tiles(Abase, Bbase, kbase, ls[0][0], ls[0][1], wave, lane);
  __syncthreads();
  int k0 = kbase + 64;
  for (int i = 0; i < 7; ++i) {
    stage_tiles(Abase, Bbase, k0, ls[1][0], ls[1][1], wave, lane);
    compute_tiles(ls[0][0], ls[0][1], acc, wr, wc, lm, lq);
    __syncthreads();
    stage_tiles(Abase, Bbase, k0 + 64, ls[0][0], ls[0][1], wave, lane);
    compute_tiles(ls[1][0], ls[1][1], acc, wr, wc, lm, lq);
    __syncthreads();
    k0 += 128;
  }
  stage_tiles(Abase, Bbase, kbase + 960, ls[1][0], ls[1][1], wave, lane);
  compute_tiles(ls[0][0], ls[0][1], acc, wr, wc, lm, lq);
  __syncthreads();
  compute_tiles(ls[1][0], ls[1][1], acc, wr, wc, lm, lq);

  // Positional partial-C accumulation: every split uses identical fragment
  // code, so lane/reg -> element mapping matches; elementwise sum across
  // splits is correct without decoding the MFMA C/D layout. Coalesced.
  float* Cbase = Cbuf + (size_t)(prod * 16 + tile) * 16384;
#pragma unroll
  for (int mi = 0; mi < 4; ++mi)
#pragma unroll
    for (int ni = 0; ni < 4; ++ni)
#pragma unroll
      for (int r = 0; r < 4; ++r) {
        int j = (mi * 4 + ni) * 4 + r;
        atomicAdd(&Cbase[j * 256 + t], acc[mi][ni][r]);
      }
}

__global__ __launch_bounds__(256) void reduce_kernel(
    const float4* __restrict__ Cbuf, float* __restrict__ out) {
  const float w[7] = {3.f, 1.f, 1.f, 1.f, -2.f, -2.f, -2.f};
  int t = threadIdx.x;
  float s = 0.f;
  int stride = gridDim.x * 256;
  for (size_t i = (size_t)blockIdx.x * 256 + t; i < CBUF_ELEMS / 4;
       i += stride) {
    float4 v = Cbuf[i];
    float ww = w[i >> 16];  // 65536 float4 per product
    s += ww * (v.x * v.x + v.y * v.y + v.z * v.z + v.w * v.w);
  }
#pragma unroll
  for (int off = 32; off > 0; off >>= 1) s += __shfl_down(s, off, 64);
  __shared__ float red[4];
  if ((t & 63) == 0) red[t >> 6] = s;
  __syncthreads();
  if (t == 0)
    atomicAdd(out, LOSS_SCALE * (red[0] + red[1] + red[2] + red[3]));
}

extern "C" void kernel_launch(void* const* d_in, const int* in_sizes, int n_in,
                              void* d_out, int out_size, void* d_ws, size_t ws_size,
                              hipStream_t stream) {
  const float* in_rgb   = (const float*)d_in[0];
  const float* in_depth = (const float*)d_in[1];
  const float* in_ir    = (const float*)d_in[2];
  const float* in_t     = (const float*)d_in[3];

  unsigned short* nT = (unsigned short*)d_ws;                    // 16 MB
  float* rscale = (float*)((char*)d_ws + NT_BYTES);              // 64 KB
  float* Cbuf   = (float*)((char*)d_ws + NT_BYTES + RSC_BYTES);  // 7.34 MB

  hipMemsetAsync(d_out, 0, out_size * sizeof(float), stream);

  rownorm_kernel<<<2048, 256, 0, stream>>>(in_rgb, in_depth, in_ir, in_t,
                                           rscale, (float4*)Cbuf);
  transpose_kernel<<<dim3(64, 4, 4), 256, 0, stream>>>(in_rgb, in_depth, in_ir,
                                                       in_t, rscale, nT);
  gram_frob_kernel<<<dim3(16, 7, 4), 256, 0, stream>>>(nT, Cbuf);
  reduce_kernel<<<128, 256, 0, stream>>>((const float4*)Cbuf, (float*)d_out);
}

// Round 4
// 120.546 us; speedup vs baseline: 1.3906x; 1.0726x over previous
//
#include <hip/hip_runtime.h>
#include <hip/hip_bf16.h>

// loss = (100/N^2) * [3*s_tt + s_rr + s_dd + s_ii - 2*(s_tr + s_td + s_ti)]
// where s_ab = || n_a^T n_b ||_F^2   (n_x = row-normalized input, N=4096, D=512)
//
// K1 rownorm:   rscale[mod][r] = 1/max(||row||,eps)                 (2048 blk)
// K2 transpose: nT[mod][c][k] = bf16(X[k][c]*rscale[k])  K-contig   (1024 blk)
// K3 gram:      7 TN-GEMMs 512x512, SPLIT-K=4 -> 448 blocks, 128x128 tiles,
//               XOR-swizzled dbuf LDS staging; partial C -> per-split slice,
//               plain coalesced float4 stores (NO atomics, no pre-zero)
// K4 reduce:    sum_w( (sum_splits Cbuf)^2 ) -> d_out

typedef __attribute__((ext_vector_type(8))) short short8;
typedef __attribute__((ext_vector_type(8))) unsigned short ushort8;
typedef __attribute__((ext_vector_type(4))) float floatx4;

#define N_ROWS 4096
#define DDIM   512
#define NT_BYTES     ((size_t)4 * DDIM * N_ROWS * 2)      // 16 MB bf16
#define RSC_BYTES    ((size_t)4 * N_ROWS * 4)             // 64 KB
#define SLICE_FLOATS ((size_t)112 * 16384)                // 1,835,008 fp32 / split
#define NSPLIT 4
#define LOSS_SCALE 5.9604644775390625e-06f                // 100 / 4096^2

__device__ __forceinline__ const float* sel_mod(int mod, const float* a,
                                                const float* b, const float* c,
                                                const float* d) {
  return mod == 0 ? a : mod == 1 ? b : mod == 2 ? c : d;
}

__global__ __launch_bounds__(256) void rownorm_kernel(
    const float* __restrict__ in0, const float* __restrict__ in1,
    const float* __restrict__ in2, const float* __restrict__ in3,
    float* __restrict__ rscale) {
  int t = threadIdx.x;
  int w = t >> 6, lane = t & 63;
  int base = blockIdx.x * 8;  // 8 rows/block, wave w does rows base+2w, +1
#pragma unroll
  for (int i = 0; i < 2; ++i) {
    int g = base + w * 2 + i;          // global row 0..16383
    int mod = g >> 12, r = g & 4095;
    const float* X = sel_mod(mod, in0, in1, in2, in3);
    const float4* rp = (const float4*)(X + (size_t)r * DDIM);
    float4 a = rp[lane];               // 1 KB dense per instr
    float4 b = rp[lane + 64];
    float ss = a.x * a.x + a.y * a.y + a.z * a.z + a.w * a.w +
               b.x * b.x + b.y * b.y + b.z * b.z + b.w * b.w;
#pragma unroll
    for (int off = 32; off > 0; off >>= 1) ss += __shfl_down(ss, off, 64);
    if (lane == 0) rscale[g] = 1.0f / fmaxf(sqrtf(ss), 1e-12f);
  }
}

__global__ __launch_bounds__(256) void transpose_kernel(
    const float* __restrict__ in0, const float* __restrict__ in1,
    const float* __restrict__ in2, const float* __restrict__ in3,
    const float* __restrict__ rscale, unsigned short* __restrict__ nT) {
  // grid: x = 64 (k-strips of 64), y = 4 (col-panels of 128), z = 4 (mod)
  int mod = blockIdx.z;
  int k0 = blockIdx.x * 64;
  int c0 = blockIdx.y * 128;
  const float* X = sel_mod(mod, in0, in1, in2, in3);

  __shared__ float lrsc[64];
  // stride 72 ushort = 36 dwords: 16B-aligned rows; ushort8 reads are
  // bank-uniform (bank = (4(c+g)+j) mod 32, exactly 8 accesses/bank).
  __shared__ unsigned short tile[128][72];

  int t = threadIdx.x;
  if (t < 64) lrsc[t] = rscale[mod * N_ROWS + k0 + t];
  __syncthreads();

#pragma unroll
  for (int it = 0; it < 8; ++it) {
    int idx = it * 256 + t;
    int r = idx >> 5;          // k-row 0..63
    int c4 = idx & 31;         // float4 index within 128-col panel
    float4 v = ((const float4*)(X + (size_t)(k0 + r) * DDIM + c0))[c4];
    float sc = lrsc[r];
    __hip_bfloat16 h0 = __float2bfloat16(v.x * sc);
    __hip_bfloat16 h1 = __float2bfloat16(v.y * sc);
    __hip_bfloat16 h2 = __float2bfloat16(v.z * sc);
    __hip_bfloat16 h3 = __float2bfloat16(v.w * sc);
    tile[c4 * 4 + 0][r] = *(unsigned short*)&h0;
    tile[c4 * 4 + 1][r] = *(unsigned short*)&h1;
    tile[c4 * 4 + 2][r] = *(unsigned short*)&h2;
    tile[c4 * 4 + 3][r] = *(unsigned short*)&h3;
  }
  __syncthreads();

#pragma unroll
  for (int it = 0; it < 4; ++it) {
    int idx = it * 256 + t;
    int c = idx >> 3;          // column 0..127
    int g = idx & 7;           // ushort8 group over k
    ushort8 v = *(const ushort8*)&tile[c][g * 8];   // ds_read_b128, conflict-free
    *(ushort8*)(nT + ((size_t)mod * DDIM + c0 + c) * N_ROWS + k0 + g * 8) = v;
  }
}

__device__ __forceinline__ void stage_tiles(
    const unsigned short* __restrict__ Abase,
    const unsigned short* __restrict__ Bbase, int k0,
    unsigned short* lsA, unsigned short* lsB, int wave, int lane) {
  // XOR swizzle: LDS slot s (=lane&7) of row r receives global chunk s ^ (r&7)
  int srow = lane >> 3;
  int scol = ((lane & 7) ^ srow) * 8;
#pragma unroll
  for (int c = 0; c < 4; ++c) {
    int base_row = wave * 32 + c * 8;  // wave-uniform
    const unsigned short* ga =
        Abase + (size_t)(base_row + srow) * N_ROWS + k0 + scol;
    const unsigned short* gb =
        Bbase + (size_t)(base_row + srow) * N_ROWS + k0 + scol;
    __builtin_amdgcn_global_load_lds(
        (__attribute__((address_space(1))) void*)(void*)ga,
        (__attribute__((address_space(3))) void*)(void*)&lsA[base_row * 64],
        16, 0, 0);
    __builtin_amdgcn_global_load_lds(
        (__attribute__((address_space(1))) void*)(void*)gb,
        (__attribute__((address_space(3))) void*)(void*)&lsB[base_row * 64],
        16, 0, 0);
  }
}

__device__ __forceinline__ void compute_tiles(
    const unsigned short* lsA, const unsigned short* lsB,
    floatx4 acc[4][4], int wr, int wc, int lm, int lq) {
#pragma unroll
  for (int ks = 0; ks < 2; ++ks) {
    int slot = (ks * 4 + lq) ^ (lm & 7);  // un-swizzle (row&7 == lm&7)
    short8 af[4], bf[4];
#pragma unroll
    for (int mi = 0; mi < 4; ++mi) {
      int row = wr + mi * 16 + lm;
      af[mi] = *(const short8*)&lsA[row * 64 + slot * 8];  // ds_read_b128
    }
#pragma unroll
    for (int ni = 0; ni < 4; ++ni) {
      int row = wc + ni * 16 + lm;
      bf[ni] = *(const short8*)&lsB[row * 64 + slot * 8];
    }
#pragma unroll
    for (int mi = 0; mi < 4; ++mi)
#pragma unroll
      for (int ni = 0; ni < 4; ++ni)
        acc[mi][ni] = __builtin_amdgcn_mfma_f32_16x16x32_bf16(
            af[mi], bf[ni], acc[mi][ni], 0, 0, 0);
  }
}

__global__ __launch_bounds__(256) void gram_frob_kernel(
    const unsigned short* __restrict__ nT, float* __restrict__ Cbuf) {
  // blockIdx: x = tile 0..15 (4x4 over 512x512), y = product 0..6, z = split 0..3
  __shared__ unsigned short ls[2][2][128 * 64];  // [buf][A/B], 64 KB

  const int pa[7] = {3, 0, 1, 2, 3, 3, 3};
  const int pb[7] = {3, 0, 1, 2, 0, 1, 2};

  int tile = blockIdx.x;
  int prod = blockIdx.y;
  int kbase = blockIdx.z * 1024;
  int a0 = (tile >> 2) * 128;
  int b0 = (tile & 3) * 128;
  const unsigned short* Abase = nT + ((size_t)pa[prod] * DDIM + a0) * N_ROWS;
  const unsigned short* Bbase = nT + ((size_t)pb[prod] * DDIM + b0) * N_ROWS;

  int t = threadIdx.x;
  int wave = t >> 6;
  int lane = t & 63;
  int wr = (wave >> 1) * 64;
  int wc = (wave & 1) * 64;
  int lm = lane & 15;
  int lq = lane >> 4;

  floatx4 zero = {0.f, 0.f, 0.f, 0.f};
  floatx4 acc[4][4];
#pragma unroll
  for (int mi = 0; mi < 4; ++mi)
#pragma unroll
    for (int ni = 0; ni < 4; ++ni) acc[mi][ni] = zero;

  // 16 chunks of K=64, double-buffered
  stage_tiles(Abase, Bbase, kbase, ls[0][0], ls[0][1], wave, lane);
  __syncthreads();
  int k0 = kbase + 64;
  for (int i = 0; i < 7; ++i) {
    stage_tiles(Abase, Bbase, k0, ls[1][0], ls[1][1], wave, lane);
    compute_tiles(ls[0][0], ls[0][1], acc, wr, wc, lm, lq);
    __syncthreads();
    stage_tiles(Abase, Bbase, k0 + 64, ls[0][0], ls[0][1], wave, lane);
    compute_tiles(ls[1][0], ls[1][1], acc, wr, wc, lm, lq);
    __syncthreads();
    k0 += 128;
  }
  stage_tiles(Abase, Bbase, kbase + 960, ls[1][0], ls[1][1], wave, lane);
  compute_tiles(ls[0][0], ls[0][1], acc, wr, wc, lm, lq);
  __syncthreads();
  compute_tiles(ls[1][0], ls[1][1], acc, wr, wc, lm, lq);

  // Positional partial-C store to this split's private slice. Every split
  // runs identical fragment code, so lane/reg -> element mapping matches and
  // elementwise cross-split summation is correct without decoding the MFMA
  // C/D layout. Plain coalesced float4 stores (16B/lane), no atomics.
  float* Cp = Cbuf + (size_t)blockIdx.z * SLICE_FLOATS +
              (size_t)(prod * 16 + tile) * 16384;
#pragma unroll
  for (int mi = 0; mi < 4; ++mi)
#pragma unroll
    for (int ni = 0; ni < 4; ++ni) {
      int j = mi * 4 + ni;
      *(floatx4*)(Cp + (size_t)(j * 256 + t) * 4) = acc[mi][ni];
    }
}

__global__ __launch_bounds__(256) void reduce_kernel(
    const float4* __restrict__ Cbuf, float* __restrict__ out) {
  const float w[7] = {3.f, 1.f, 1.f, 1.f, -2.f, -2.f, -2.f};
  const size_t S4 = SLICE_FLOATS / 4;  // float4 per slice
  int t = threadIdx.x;
  float s = 0.f;
  size_t stride = (size_t)gridDim.x * 256;
  for (size_t i = (size_t)blockIdx.x * 256 + t; i < S4; i += stride) {
    float4 a = Cbuf[i];
    float4 b = Cbuf[i + S4];
    float4 c = Cbuf[i + 2 * S4];
    float4 d = Cbuf[i + 3 * S4];
    float vx = a.x + b.x + c.x + d.x;
    float vy = a.y + b.y + c.y + d.y;
    float vz = a.z + b.z + c.z + d.z;
    float vw = a.w + b.w + c.w + d.w;
    float ww = w[i >> 16];  // 65536 float4 per product
    s += ww * (vx * vx + vy * vy + vz * vz + vw * vw);
  }
#pragma unroll
  for (int off = 32; off > 0; off >>= 1) s += __shfl_down(s, off, 64);
  __shared__ float red[4];
  if ((t & 63) == 0) red[t >> 6] = s;
  __syncthreads();
  if (t == 0)
    atomicAdd(out, LOSS_SCALE * (red[0] + red[1] + red[2] + red[3]));
}

extern "C" void kernel_launch(void* const* d_in, const int* in_sizes, int n_in,
                              void* d_out, int out_size, void* d_ws, size_t ws_size,
                              hipStream_t stream) {
  const float* in_rgb   = (const float*)d_in[0];
  const float* in_depth = (const float*)d_in[1];
  const float* in_ir    = (const float*)d_in[2];
  const float* in_t     = (const float*)d_in[3];

  unsigned short* nT = (unsigned short*)d_ws;                    // 16 MB
  float* rscale = (float*)((char*)d_ws + NT_BYTES);              // 64 KB
  float* Cbuf   = (float*)((char*)d_ws + NT_BYTES + RSC_BYTES);  // 29.4 MB

  hipMemsetAsync(d_out, 0, out_size * sizeof(float), stream);

  rownorm_kernel<<<2048, 256, 0, stream>>>(in_rgb, in_depth, in_ir, in_t,
                                           rscale);
  transpose_kernel<<<dim3(64, 4, 4), 256, 0, stream>>>(in_rgb, in_depth, in_ir,
                                                       in_t, rscale, nT);
  gram_frob_kernel<<<dim3(16, 7, NSPLIT), 256, 0, stream>>>(nT, Cbuf);
  reduce_kernel<<<448, 256, 0, stream>>>((const float4*)Cbuf, (float*)d_out);
}

// Round 5
// 120.292 us; speedup vs baseline: 1.3935x; 1.0021x over previous
//
#include <hip/hip_runtime.h>
#include <hip/hip_bf16.h>

// loss = (100/N^2) * [3*s_tt + s_rr + s_dd + s_ii - 2*(s_tr + s_td + s_ti)]
// where s_ab = || n_a^T n_b ||_F^2   (n_x = row-normalized input, N=4096, D=512)
//
// fp8 pipeline (x16 pre-scale folded into normalization; /16^4 at the end;
// Frobenius structure => immune to any consistent K-permutation or C/D layout):
// K1 preprocess: fused rownorm + scale(16/||r||) + fp8 cast + transpose
//                -> nT8[mod][c][k]  (8 MB, K-contiguous)          (256 blk)
// K2 gram:       7 TN-GEMMs 512x512 fp8, SPLIT-K=4 -> 448 blocks, 128x128
//                tiles, K-chunk 128, XOR-swizzled dbuf LDS (64 KB), partial C
//                -> per-split slice, plain coalesced float4 stores
// K3 reduce:     sum_w( (sum_splits Cbuf)^2 ) -> d_out

typedef __attribute__((ext_vector_type(4))) float floatx4;
typedef __attribute__((ext_vector_type(8))) unsigned short ushort8;

#define N_ROWS 4096
#define DDIM   512
#define NT8_BYTES    ((size_t)4 * DDIM * N_ROWS)          // 8 MB fp8
#define SLICE_FLOATS ((size_t)112 * 16384)                // 1,835,008 fp32/split
#define NSPLIT 4
// 100 / (4096^2 * 16^4)
#define LOSS_SCALE 9.094947017729282e-11f

__device__ __forceinline__ const float* sel_mod(int mod, const float* a,
                                                const float* b, const float* c,
                                                const float* d) {
  return mod == 0 ? a : mod == 1 ? b : mod == 2 ? c : d;
}

__global__ __launch_bounds__(256) void preprocess_kernel(
    const float* __restrict__ in0, const float* __restrict__ in1,
    const float* __restrict__ in2, const float* __restrict__ in3,
    unsigned char* __restrict__ nT8) {
  // grid: x = 64 (k-strips of 64 rows), y = 4 (mod). 256 threads = 4 waves.
  int mod = blockIdx.y;
  int k0 = blockIdx.x * 64;
  const float* X = sel_mod(mod, in0, in1, in2, in3) + (size_t)k0 * DDIM;

  __shared__ float rsc[64];
  __shared__ unsigned short tile[128][72];  // bf16 intermediate, 16B-aligned rows

  int t = threadIdx.x;
  int w = t >> 6, lane = t & 63;

  // phase A: row norms for this strip (16 rows per wave)
#pragma unroll
  for (int i = 0; i < 16; ++i) {
    int r = w * 16 + i;
    const float4* rp = (const float4*)(X + (size_t)r * DDIM);
    float4 a = rp[lane];
    float4 b = rp[lane + 64];
    float ss = a.x * a.x + a.y * a.y + a.z * a.z + a.w * a.w +
               b.x * b.x + b.y * b.y + b.z * b.z + b.w * b.w;
#pragma unroll
    for (int off = 32; off > 0; off >>= 1) ss += __shfl_down(ss, off, 64);
    if (lane == 0) rsc[r] = 16.0f / fmaxf(sqrtf(ss), 1e-12f);  // x16 folded
  }
  __syncthreads();

  // phase B: 4 panels of 128 cols; rows re-read from L2
  for (int p = 0; p < 4; ++p) {
#pragma unroll
    for (int it = 0; it < 8; ++it) {
      int idx = it * 256 + t;
      int r = idx >> 5;          // k-row 0..63
      int c4 = idx & 31;         // float4 index within 128-col panel
      float4 v = ((const float4*)(X + (size_t)r * DDIM + p * 128))[c4];
      float sc = rsc[r];
      __hip_bfloat16 h0 = __float2bfloat16(v.x * sc);
      __hip_bfloat16 h1 = __float2bfloat16(v.y * sc);
      __hip_bfloat16 h2 = __float2bfloat16(v.z * sc);
      __hip_bfloat16 h3 = __float2bfloat16(v.w * sc);
      tile[c4 * 4 + 0][r] = *(unsigned short*)&h0;
      tile[c4 * 4 + 1][r] = *(unsigned short*)&h1;
      tile[c4 * 4 + 2][r] = *(unsigned short*)&h2;
      tile[c4 * 4 + 3][r] = *(unsigned short*)&h3;
    }
    __syncthreads();
#pragma unroll
    for (int it = 0; it < 2; ++it) {
      int idx = it * 256 + t;
      int c = idx >> 2;          // column 0..127
      int g = idx & 3;           // 16-byte k-group
      ushort8 u0 = *(const ushort8*)&tile[c][g * 16];
      ushort8 u1 = *(const ushort8*)&tile[c][g * 16 + 8];
      float f[16];
#pragma unroll
      for (int j = 0; j < 8; ++j) {
        f[j] = __uint_as_float(((unsigned int)(unsigned short)u0[j]) << 16);
        f[8 + j] = __uint_as_float(((unsigned int)(unsigned short)u1[j]) << 16);
      }
      unsigned int wds[4];
#pragma unroll
      for (int q = 0; q < 4; ++q) {
        unsigned int pk = __builtin_amdgcn_cvt_pk_fp8_f32(f[4 * q], f[4 * q + 1], 0, 0);
        pk = __builtin_amdgcn_cvt_pk_fp8_f32(f[4 * q + 2], f[4 * q + 3], pk, 1);
        wds[q] = pk;  // byte order within group is a fixed k-perm: harmless
      }
      uint4 out = {wds[0], wds[1], wds[2], wds[3]};
      *(uint4*)(nT8 + ((size_t)(mod * DDIM + p * 128 + c)) * N_ROWS + k0 +
                g * 16) = out;
    }
    __syncthreads();
  }
}

__device__ __forceinline__ void stage_tiles(
    const unsigned char* __restrict__ Abase,
    const unsigned char* __restrict__ Bbase, int k0,
    unsigned char* lsA, unsigned char* lsB, int wave, int lane) {
  // 16B-chunk XOR swizzle: LDS slot s of row r holds global chunk s^((r>>1)&7)
  int rr = lane >> 3;          // row 0..7 within 8-row staging group
  int s = lane & 7;            // 16B slot within 128B row
#pragma unroll
  for (int c = 0; c < 4; ++c) {
    int base = wave * 32 + c * 8;  // wave-uniform
    int row = base + rr;
    int gc = s ^ ((row >> 1) & 7);
    const unsigned char* ga = Abase + (size_t)row * N_ROWS + k0 + gc * 16;
    const unsigned char* gb = Bbase + (size_t)row * N_ROWS + k0 + gc * 16;
    __builtin_amdgcn_global_load_lds(
        (__attribute__((address_space(1))) void*)(void*)ga,
        (__attribute__((address_space(3))) void*)(void*)&lsA[base * 128],
        16, 0, 0);
    __builtin_amdgcn_global_load_lds(
        (__attribute__((address_space(1))) void*)(void*)gb,
        (__attribute__((address_space(3))) void*)(void*)&lsB[base * 128],
        16, 0, 0);
  }
}

__device__ __forceinline__ void compute_tiles(
    const unsigned char* lsA, const unsigned char* lsB,
    floatx4 acc[4][4], int wr, int wc, int lm, int lq) {
#pragma unroll
  for (int ks = 0; ks < 4; ++ks) {
    int j = ks * 4 + lq;       // 8B unit within 128B row
    int cg = j >> 1;
    int sub = (j & 1) * 8;
    long long af[4], bf[4];
#pragma unroll
    for (int mi = 0; mi < 4; ++mi) {
      int row = wr + mi * 16 + lm;
      int slot = cg ^ ((row >> 1) & 7);
      af[mi] = *(const long long*)&lsA[row * 128 + slot * 16 + sub];
    }
#pragma unroll
    for (int ni = 0; ni < 4; ++ni) {
      int row = wc + ni * 16 + lm;
      int slot = cg ^ ((row >> 1) & 7);
      bf[ni] = *(const long long*)&lsB[row * 128 + slot * 16 + sub];
    }
#pragma unroll
    for (int mi = 0; mi < 4; ++mi)
#pragma unroll
      for (int ni = 0; ni < 4; ++ni)
        acc[mi][ni] = __builtin_amdgcn_mfma_f32_16x16x32_fp8_fp8(
            af[mi], bf[ni], acc[mi][ni], 0, 0, 0);
  }
}

__global__ __launch_bounds__(256) void gram_frob_kernel(
    const unsigned char* __restrict__ nT8, float* __restrict__ Cbuf) {
  // blockIdx: x = tile 0..15 (4x4 over 512x512), y = product 0..6, z = split 0..3
  __shared__ unsigned char ls[2][2][128 * 128];  // [buf][A/B], 64 KB

  const int pa[7] = {3, 0, 1, 2, 3, 3, 3};
  const int pb[7] = {3, 0, 1, 2, 0, 1, 2};

  int tile = blockIdx.x;
  int prod = blockIdx.y;
  int kbase = blockIdx.z * 1024;
  int a0 = (tile >> 2) * 128;
  int b0 = (tile & 3) * 128;
  const unsigned char* Abase = nT8 + ((size_t)pa[prod] * DDIM + a0) * N_ROWS;
  const unsigned char* Bbase = nT8 + ((size_t)pb[prod] * DDIM + b0) * N_ROWS;

  int t = threadIdx.x;
  int wave = t >> 6;
  int lane = t & 63;
  int wr = (wave >> 1) * 64;
  int wc = (wave & 1) * 64;
  int lm = lane & 15;
  int lq = lane >> 4;

  floatx4 zero = {0.f, 0.f, 0.f, 0.f};
  floatx4 acc[4][4];
#pragma unroll
  for (int mi = 0; mi < 4; ++mi)
#pragma unroll
    for (int ni = 0; ni < 4; ++ni) acc[mi][ni] = zero;

  // 8 chunks of K=128, double-buffered
  stage_tiles(Abase, Bbase, kbase, ls[0][0], ls[0][1], wave, lane);
  __syncthreads();
  int k0 = kbase + 128;
  for (int i = 0; i < 3; ++i) {
    stage_tiles(Abase, Bbase, k0, ls[1][0], ls[1][1], wave, lane);
    compute_tiles(ls[0][0], ls[0][1], acc, wr, wc, lm, lq);
    __syncthreads();
    stage_tiles(Abase, Bbase, k0 + 128, ls[0][0], ls[0][1], wave, lane);
    compute_tiles(ls[1][0], ls[1][1], acc, wr, wc, lm, lq);
    __syncthreads();
    k0 += 256;
  }
  stage_tiles(Abase, Bbase, kbase + 896, ls[1][0], ls[1][1], wave, lane);
  compute_tiles(ls[0][0], ls[0][1], acc, wr, wc, lm, lq);
  __syncthreads();
  compute_tiles(ls[1][0], ls[1][1], acc, wr, wc, lm, lq);

  // Positional partial-C store to this split's private slice (identical
  // fragment code across splits => elementwise cross-split sum is correct
  // regardless of MFMA C/D layout). Coalesced float4, no atomics.
  float* Cp = Cbuf + (size_t)blockIdx.z * SLICE_FLOATS +
              (size_t)(prod * 16 + tile) * 16384;
#pragma unroll
  for (int mi = 0; mi < 4; ++mi)
#pragma unroll
    for (int ni = 0; ni < 4; ++ni) {
      int j = mi * 4 + ni;
      *(floatx4*)(Cp + (size_t)(j * 256 + t) * 4) = acc[mi][ni];
    }
}

__global__ __launch_bounds__(256) void reduce_kernel(
    const float4* __restrict__ Cbuf, float* __restrict__ out) {
  const float w[7] = {3.f, 1.f, 1.f, 1.f, -2.f, -2.f, -2.f};
  const size_t S4 = SLICE_FLOATS / 4;  // float4 per slice
  int t = threadIdx.x;
  float s = 0.f;
  size_t stride = (size_t)gridDim.x * 256;
  for (size_t i = (size_t)blockIdx.x * 256 + t; i < S4; i += stride) {
    float4 a = Cbuf[i];
    float4 b = Cbuf[i + S4];
    float4 c = Cbuf[i + 2 * S4];
    float4 d = Cbuf[i + 3 * S4];
    float vx = a.x + b.x + c.x + d.x;
    float vy = a.y + b.y + c.y + d.y;
    float vz = a.z + b.z + c.z + d.z;
    float vw = a.w + b.w + c.w + d.w;
    float ww = w[i >> 16];  // 65536 float4 per product
    s += ww * (vx * vx + vy * vy + vz * vz + vw * vw);
  }
#pragma unroll
  for (int off = 32; off > 0; off >>= 1) s += __shfl_down(s, off, 64);
  __shared__ float red[4];
  if ((t & 63) == 0) red[t >> 6] = s;
  __syncthreads();
  if (t == 0)
    atomicAdd(out, LOSS_SCALE * (red[0] + red[1] + red[2] + red[3]));
}

extern "C" void kernel_launch(void* const* d_in, const int* in_sizes, int n_in,
                              void* d_out, int out_size, void* d_ws, size_t ws_size,
                              hipStream_t stream) {
  const float* in_rgb   = (const float*)d_in[0];
  const float* in_depth = (const float*)d_in[1];
  const float* in_ir    = (const float*)d_in[2];
  const float* in_t     = (const float*)d_in[3];

  unsigned char* nT8 = (unsigned char*)d_ws;                 // 8 MB fp8
  float* Cbuf = (float*)((char*)d_ws + NT8_BYTES);           // 29.4 MB

  hipMemsetAsync(d_out, 0, out_size * sizeof(float), stream);

  preprocess_kernel<<<dim3(64, 4), 256, 0, stream>>>(in_rgb, in_depth, in_ir,
                                                     in_t, nT8);
  gram_frob_kernel<<<dim3(16, 7, NSPLIT), 256, 0, stream>>>(nT8, Cbuf);
  reduce_kernel<<<448, 256, 0, stream>>>((const float4*)Cbuf, (float*)d_out);
}